// Round 8
// baseline (682.894 us; speedup 1.0000x reference)
//
#include <hip/hip_runtime.h>

typedef unsigned short u16;
typedef unsigned int u32;

__device__ __forceinline__ float2 up2(u32 u){
  union { u32 i; float f; } a, b;
  a.i = u << 16; b.i = u & 0xffff0000u;
  float2 r; r.x = a.f; r.y = b.f; return r;
}
__device__ __forceinline__ u16 f2bf(float f){
  union { float f; u32 i; } v; v.f = f;
  u32 x = v.i;
  return (u16)((x + 0x7fffu + ((x >> 16) & 1u)) >> 16);
}
__device__ __forceinline__ u32 pk2(float a, float b){
  return (u32)f2bf(a) | ((u32)f2bf(b) << 16);
}
__device__ __forceinline__ float silu_f(float x){ return x / (1.f + __expf(-x)); }
__device__ __forceinline__ float softplus_f(float x){
  return fmaxf(x, 0.f) + log1pf(__expf(-fabsf(x)));
}

// ---- transpose weights, A = -exp(A_log) --------------------------------
__global__ __launch_bounds__(256) void k_prep(
    const float* __restrict__ ipw, const float* __restrict__ xpw,
    const float* __restrict__ dtw, const float* __restrict__ opw,
    const float* __restrict__ w1, const float* __restrict__ w2,
    const float* __restrict__ w3, const float* __restrict__ alog,
    float* __restrict__ ipT, float* __restrict__ xpT,
    float* __restrict__ dtT, float* __restrict__ opT,
    float* __restrict__ w1T, float* __restrict__ w2T,
    float* __restrict__ w3T, float* __restrict__ Aneg)
{
  int t = blockIdx.x * 256 + threadIdx.x;
  if (t < 16384){ int o = t >> 6, c = t & 63; ipT[c * 256 + o] = ipw[t]; }
  if (t < 8192){ int o = t >> 7, d = t & 127; xpT[d * 64 + o] = xpw[t]; }
  if (t < 4096){ int d = t >> 5, r = t & 31; dtT[r * 128 + d] = dtw[t]; }
  if (t < 8192){ int o = t >> 7, d = t & 127; opT[d * 64 + o] = opw[t]; }
  if (t < 4096){ int o = t >> 6, c = t & 63;
                 w1T[c*64+o] = w1[t]; w2T[c*64+o] = w2[t]; w3T[c*64+o] = w3[t]; }
  if (t < 2048){ Aneg[t] = -__expf(alog[t]); }
}

// ---- fully fused: convin + 6 mamba blocks + conv3 ----------------------
// 256 blocks (1/CU). Block owns 32 positions, computes 48 (halo 8/side,
// need 6 for the 6 chained radius-1 convs). 1024 threads = 16 waves x
// 3 positions/wave. Lane owns d_inner channels d0=lane, d1=64+lane.
// h state: bf16-packed, resident in VGPRs across all 6 steps: 48 u32/thread.
// A 1024-thread block forces 4 waves/SIMD -> VGPR budget 128; total live
// state (~120) fits, eliminating the ~1.28 GB/dispatch scratch spill the
// 512-thread/96-u32-h version suffered at the same 128 budget.
#define CPB 48
#define PPW 3

__global__ __launch_bounds__(1024) void k_fused(
    const float* __restrict__ rgb, const float* __restrict__ dte,
    const float* __restrict__ w1T, const float* __restrict__ b1,
    const float* __restrict__ w2T, const float* __restrict__ b2,
    const float* __restrict__ w3T, const float* __restrict__ b3,
    const float* __restrict__ normw, const float* __restrict__ ipT,
    const float* __restrict__ xpT, const float* __restrict__ dtT,
    const float* __restrict__ opT, const float* __restrict__ Aneg,
    const float* __restrict__ c1w, const float* __restrict__ c1b,
    const float* __restrict__ dtb, const float* __restrict__ Dpw,
    float* __restrict__ outc, float* __restrict__ hfin)
{
  __shared__ __align__(16) float xcp[CPB][128];   // conv input (in_proj x half)
  __shared__ __align__(16) float xcs[CPB][128];   // conv out, reused as y*z
  __shared__ __align__(16) float dblS[CPB][64];   // x_proj out (dt|B|C); later out6
  __shared__ __align__(16) float xns[CPB][64];    // normalized x
  __shared__ __align__(16) float bA[CPB][64];     // rgbp base
  __shared__ __align__(16) float bB[CPB][64];     // dtep base
  __shared__ __align__(16) float ansS[16][129];   // A (s-major, padded)
  __shared__ __align__(16) float xpW[8192];       // x_proj weights
  __shared__ __align__(16) float dtW[4096];       // dt_proj weights

  const int tid = threadIdx.x;
  const int wv = tid >> 6, lane = tid & 63;
  const int b = blockIdx.x;
  const int batch = b >> 7;
  const int lbase = ((b & 127) << 5) - 8;         // local l of computed pos 0
  const int cpw = wv * PPW;
  const int d0 = lane, d1 = 64 + lane;

  // stage shared weights into LDS
  for (int i = tid; i < 8192; i += 1024) xpW[i] = xpT[i];
  for (int i = tid; i < 4096; i += 1024) dtW[i] = dtT[i];
  for (int i = tid; i < 2048; i += 1024) ansS[i & 15][i >> 4] = Aneg[i];

  // per-lane constants
  const float cw00 = c1w[d0*3+0], cw01 = c1w[d0*3+1], cw02 = c1w[d0*3+2];
  const float cw10 = c1w[d1*3+0], cw11 = c1w[d1*3+1], cw12 = c1w[d1*3+2];
  const float cb0 = c1b[d0], cb1 = c1b[d1];
  const float tb0 = dtb[d0], tb1 = dtb[d1];
  const float dp0 = Dpw[d0], dp1 = Dpw[d1];
  const float nw = normw[lane];

  int lp[PPW];
  #pragma unroll
  for (int p = 0; p < PPW; p++) lp[p] = lbase + cpw + p;   // unclamped local l

  // ---- input 1x1 convs: bA = rgbp, bB = dtep (halo reads clamped) ------
  {
    const float* rp = rgb + (size_t)batch * 262144;
    const float* dq_ = dte + (size_t)batch * 262144;
    int lc[PPW];
    #pragma unroll
    for (int p = 0; p < PPW; p++) lc[p] = min(max(lp[p], 0), 4095);
    float accA[PPW], accB[PPW];
    float bb1 = b1[lane], bb2 = b2[lane];
    #pragma unroll
    for (int p = 0; p < PPW; p++){ accA[p] = bb1; accB[p] = bb2; }
    #pragma unroll 4
    for (int c = 0; c < 64; c++){
      float wA = w1T[c*64 + lane], wB = w2T[c*64 + lane];
      const float* rc = rp + c*4096;
      const float* dc = dq_ + c*4096;
      #pragma unroll
      for (int p = 0; p < PPW; p++){
        accA[p] = fmaf(wA, rc[lc[p]], accA[p]);
        accB[p] = fmaf(wB, dc[lc[p]], accB[p]);
      }
    }
    #pragma unroll
    for (int p = 0; p < PPW; p++){ bA[cpw+p][lane] = accA[p]; bB[cpw+p][lane] = accB[p]; }
  }

  // ---- pre: rmsnorm(rgbp) + in_proj -> xcp, zs (step 0 input) ----------
  float xnr[PPW], zs0[PPW], zs1[PPW];
  {
    #pragma unroll
    for (int p = 0; p < PPW; p++){
      float v = bA[cpw+p][lane];
      float ss = v * v;
      for (int m = 32; m > 0; m >>= 1) ss += __shfl_xor(ss, m);
      v = v * rsqrtf(ss * (1.f/64.f) + 1e-5f) * nw;
      xnr[p] = v; xns[cpw+p][lane] = v;
    }
    float a0[PPW]={}, a1[PPW]={}, a2[PPW]={}, a3[PPW]={};
    #pragma unroll 4
    for (int c = 0; c < 64; c++){
      float w0 = ipT[c*256 + lane];
      float w1 = ipT[c*256 + 64 + lane];
      float w2 = ipT[c*256 + 128 + lane];
      float w3 = ipT[c*256 + 192 + lane];
      #pragma unroll
      for (int p = 0; p < PPW; p++){
        float xv = xns[cpw+p][c];
        a0[p]=fmaf(w0,xv,a0[p]); a1[p]=fmaf(w1,xv,a1[p]);
        a2[p]=fmaf(w2,xv,a2[p]); a3[p]=fmaf(w3,xv,a3[p]);
      }
    }
    #pragma unroll
    for (int p = 0; p < PPW; p++){
      xcp[cpw+p][d0] = a0[p]; xcp[cpw+p][d1] = a1[p];
      zs0[p] = silu_f(a2[p]); zs1[p] = silu_f(a3[p]);
    }
  }

  // h state, bf16-packed (s even -> low, s odd -> high). Zero-init == hasH=0.
  u32 hp0[PPW][8] = {}, hp1[PPW][8] = {};

  #pragma unroll 1
  for (int k = 0; k < 6; k++){
    __syncthreads();                       // all waves' xcp (and LDS weights) ready

    // depthwise conv(3) + silu; guards: LDS bound (cp) and batch pad (l)
    float xc0[PPW], xc1[PPW];
    #pragma unroll
    for (int p = 0; p < PPW; p++){
      int cp = cpw + p;
      float am0=0.f, am1=0.f, ap0=0.f, ap1=0.f;
      if (cp > 0 && lp[p] > 0)       { am0 = xcp[cp-1][d0]; am1 = xcp[cp-1][d1]; }
      float a00 = xcp[cp][d0], a01 = xcp[cp][d1];
      if (cp < CPB-1 && lp[p] < 4095){ ap0 = xcp[cp+1][d0]; ap1 = xcp[cp+1][d1]; }
      float v0 = silu_f(fmaf(cw00,am0, fmaf(cw01,a00, fmaf(cw02,ap0, cb0))));
      float v1 = silu_f(fmaf(cw10,am1, fmaf(cw11,a01, fmaf(cw12,ap1, cb1))));
      xc0[p] = v0; xc1[p] = v1;
      xcs[cp][d0] = v0; xcs[cp][d1] = v1;
    }
    __syncthreads();                       // conv reads done; xcp may be overwritten

    // x_proj -> dblS[cp][o]  (o = lane)
    {
      float xa[PPW] = {};
      #pragma unroll 2
      for (int dq = 0; dq < 32; dq++){
        float w0 = xpW[(dq*4+0)*64 + lane], w1 = xpW[(dq*4+1)*64 + lane];
        float w2 = xpW[(dq*4+2)*64 + lane], w3 = xpW[(dq*4+3)*64 + lane];
        #pragma unroll
        for (int p = 0; p < PPW; p++){
          float4 xv = *(const float4*)&xcs[cpw+p][dq*4];
          xa[p] = fmaf(w0,xv.x, fmaf(w1,xv.y, fmaf(w2,xv.z, fmaf(w3,xv.w, xa[p]))));
        }
      }
      #pragma unroll
      for (int p = 0; p < PPW; p++) dblS[cpw+p][lane] = xa[p];
    }

    // dt_proj + softplus
    float dl0[PPW], dl1[PPW];
    {
      float da0[PPW], da1[PPW];
      #pragma unroll
      for (int p = 0; p < PPW; p++){ da0[p] = tb0; da1[p] = tb1; }
      #pragma unroll 4
      for (int r = 0; r < 32; r++){
        float w0 = dtW[r*128 + d0], w1 = dtW[r*128 + d1];
        #pragma unroll
        for (int p = 0; p < PPW; p++){
          float bv = dblS[cpw+p][r];
          da0[p] = fmaf(w0, bv, da0[p]); da1[p] = fmaf(w1, bv, da1[p]);
        }
      }
      #pragma unroll
      for (int p = 0; p < PPW; p++){ dl0[p] = softplus_f(da0[p]); dl1[p] = softplus_f(da1[p]); }
    }

    // h update + y (registers; bf16 repack except last step -> fp32 store)
    float y0[PPW] = {}, y1[PPW] = {};
    float bx0[PPW], bx1[PPW];
    #pragma unroll
    for (int p = 0; p < PPW; p++){ bx0[p] = dl0[p]*xc0[p]; bx1[p] = dl1[p]*xc1[p]; }
    if (k < 5){
      #pragma unroll
      for (int q = 0; q < 8; q++){
        float a0e = ansS[2*q][d0], a0o = ansS[2*q+1][d0];
        float a1e = ansS[2*q][d1], a1o = ansS[2*q+1][d1];
        #pragma unroll
        for (int p = 0; p < PPW; p++){
          int cp = cpw + p;
          float2 Bv = *(const float2*)&dblS[cp][32 + 2*q];
          float2 Cv = *(const float2*)&dblS[cp][48 + 2*q];
          float2 h0 = up2(hp0[p][q]);
          float2 h1 = up2(hp1[p][q]);
          float n0e = fmaf(__expf(dl0[p]*a0e), h0.x, bx0[p]*Bv.x);
          float n0o = fmaf(__expf(dl0[p]*a0o), h0.y, bx0[p]*Bv.y);
          float n1e = fmaf(__expf(dl1[p]*a1e), h1.x, bx1[p]*Bv.x);
          float n1o = fmaf(__expf(dl1[p]*a1o), h1.y, bx1[p]*Bv.y);
          y0[p] = fmaf(n0e, Cv.x, y0[p]); y0[p] = fmaf(n0o, Cv.y, y0[p]);
          y1[p] = fmaf(n1e, Cv.x, y1[p]); y1[p] = fmaf(n1o, Cv.y, y1[p]);
          hp0[p][q] = pk2(n0e, n0o);
          hp1[p][q] = pk2(n1e, n1o);
        }
      }
    } else {
      #pragma unroll
      for (int q = 0; q < 8; q++){
        float a0e = ansS[2*q][d0], a0o = ansS[2*q+1][d0];
        float a1e = ansS[2*q][d1], a1o = ansS[2*q+1][d1];
        #pragma unroll
        for (int p = 0; p < PPW; p++){
          int cp = cpw + p;
          float2 Bv = *(const float2*)&dblS[cp][32 + 2*q];
          float2 Cv = *(const float2*)&dblS[cp][48 + 2*q];
          float2 h0 = up2(hp0[p][q]);
          float2 h1 = up2(hp1[p][q]);
          float n0e = fmaf(__expf(dl0[p]*a0e), h0.x, bx0[p]*Bv.x);
          float n0o = fmaf(__expf(dl0[p]*a0o), h0.y, bx0[p]*Bv.y);
          float n1e = fmaf(__expf(dl1[p]*a1e), h1.x, bx1[p]*Bv.x);
          float n1o = fmaf(__expf(dl1[p]*a1o), h1.y, bx1[p]*Bv.y);
          y0[p] = fmaf(n0e, Cv.x, y0[p]); y0[p] = fmaf(n0o, Cv.y, y0[p]);
          y1[p] = fmaf(n1e, Cv.x, y1[p]); y1[p] = fmaf(n1o, Cv.y, y1[p]);
          if (cp >= 8 && cp < 40){
            size_t nI = (size_t)b*32 + (size_t)(cp - 8);
            float2 s0; s0.x = n0e; s0.y = n0o;
            float2 s1; s1.x = n1e; s1.y = n1o;
            *(float2*)(hfin + nI*2048 + (size_t)d0*16 + 2*q) = s0;
            *(float2*)(hfin + nI*2048 + (size_t)d1*16 + 2*q) = s1;
          }
        }
      }
    }

    // finish y, gate by silu(z) -> xcs (reused as yz buffer)
    #pragma unroll
    for (int p = 0; p < PPW; p++){
      int cp = cpw + p;
      float yy0 = fmaf(dp0, xc0[p], y0[p]);
      float yy1 = fmaf(dp1, xc1[p], y1[p]);
      xcs[cp][d0] = yy0 * zs0[p];
      xcs[cp][d1] = yy1 * zs1[p];
    }

    // out_proj
    float oa[PPW] = {};
    #pragma unroll 2
    for (int dq = 0; dq < 32; dq++){
      float w0 = opT[(dq*4+0)*64 + lane], w1 = opT[(dq*4+1)*64 + lane];
      float w2 = opT[(dq*4+2)*64 + lane], w3 = opT[(dq*4+3)*64 + lane];
      #pragma unroll
      for (int p = 0; p < PPW; p++){
        float4 yv = *(const float4*)&xcs[cpw+p][dq*4];
        oa[p] = fmaf(w0,yv.x, fmaf(w1,yv.y, fmaf(w2,yv.z, fmaf(w3,yv.w, oa[p]))));
      }
    }

    if (k < 5){
      // residual + base + rmsnorm + in_proj for next step
      const float (*bs_)[64] = (k & 1) ? bA : bB;
      #pragma unroll
      for (int p = 0; p < PPW; p++){
        int cp = cpw + p;
        float v = oa[p] + xnr[p] + bs_[cp][lane];
        float ss = v * v;
        for (int m = 32; m > 0; m >>= 1) ss += __shfl_xor(ss, m);
        v = v * rsqrtf(ss * (1.f/64.f) + 1e-5f) * nw;
        xnr[p] = v; xns[cp][lane] = v;
      }
      float a0[PPW]={}, a1[PPW]={}, a2[PPW]={}, a3[PPW]={};
      #pragma unroll 4
      for (int c = 0; c < 64; c++){
        float w0 = ipT[c*256 + lane];
        float w1 = ipT[c*256 + 64 + lane];
        float w2 = ipT[c*256 + 128 + lane];
        float w3 = ipT[c*256 + 192 + lane];
        #pragma unroll
        for (int p = 0; p < PPW; p++){
          float xv = xns[cpw+p][c];
          a0[p]=fmaf(w0,xv,a0[p]); a1[p]=fmaf(w1,xv,a1[p]);
          a2[p]=fmaf(w2,xv,a2[p]); a3[p]=fmaf(w3,xv,a3[p]);
        }
      }
      #pragma unroll
      for (int p = 0; p < PPW; p++){
        int cp = cpw + p;
        xcp[cp][d0] = a0[p]; xcp[cp][d1] = a1[p];
        zs0[p] = silu_f(a2[p]); zs1[p] = silu_f(a3[p]);
      }
    } else {
      #pragma unroll
      for (int p = 0; p < PPW; p++) dblS[cpw+p][lane] = oa[p] + xnr[p];  // out6
    }
  }

  // ---- final 1x1 conv (wave-local rows of dblS) ------------------------
  {
    float o3[PPW];
    float bb3 = b3[lane];
    #pragma unroll
    for (int p = 0; p < PPW; p++) o3[p] = bb3;
    #pragma unroll 2
    for (int cq = 0; cq < 16; cq++){
      float w0 = w3T[(cq*4+0)*64 + lane], w1 = w3T[(cq*4+1)*64 + lane];
      float w2 = w3T[(cq*4+2)*64 + lane], w3v = w3T[(cq*4+3)*64 + lane];
      #pragma unroll
      for (int p = 0; p < PPW; p++){
        float4 vv = *(const float4*)&dblS[cpw+p][cq*4];
        o3[p] = fmaf(w0,vv.x, fmaf(w1,vv.y, fmaf(w2,vv.z, fmaf(w3v,vv.w, o3[p]))));
      }
    }
    #pragma unroll
    for (int p = 0; p < PPW; p++){
      int cp = cpw + p;
      if (cp >= 8 && cp < 40)
        outc[(size_t)batch*262144 + (size_t)lane*4096 + lp[p]] = o3[p];
    }
  }
}

extern "C" void kernel_launch(void* const* d_in, const int* in_sizes, int n_in,
                              void* d_out, int out_size, void* d_ws, size_t ws_size,
                              hipStream_t stream)
{
  const float* rgb  = (const float*)d_in[0];
  const float* dte  = (const float*)d_in[1];
  const float* w1   = (const float*)d_in[2];
  const float* b1   = (const float*)d_in[3];
  const float* w2   = (const float*)d_in[4];
  const float* b2   = (const float*)d_in[5];
  const float* w3   = (const float*)d_in[6];
  const float* b3   = (const float*)d_in[7];
  const float* nrm  = (const float*)d_in[8];
  const float* ipw  = (const float*)d_in[9];
  const float* c1w  = (const float*)d_in[10];
  const float* c1b  = (const float*)d_in[11];
  const float* xpw  = (const float*)d_in[12];
  const float* dtw  = (const float*)d_in[13];
  const float* dtb  = (const float*)d_in[14];
  const float* alog = (const float*)d_in[15];
  const float* Dpw  = (const float*)d_in[16];
  const float* opw  = (const float*)d_in[17];

  float* outc = (float*)d_out;
  float* hfin = outc + 524288;          // final fp32 h lives in d_out

  float* wb   = (float*)d_ws;
  float* ipT  = wb;                     // [64][256]
  float* xpT  = wb + 16384;             // [128][64]
  float* dtT  = wb + 24576;             // [32][128]
  float* opT  = wb + 28672;             // [128][64]
  float* w1T  = wb + 36864;             // [64][64]
  float* w2T  = wb + 40960;
  float* w3T  = wb + 45056;
  float* Aneg = wb + 49152;             // [128][16]

  k_prep<<<64, 256, 0, stream>>>(ipw, xpw, dtw, opw, w1, w2, w3, alog,
                                 ipT, xpT, dtT, opT, w1T, w2T, w3T, Aneg);
  k_fused<<<256, 1024, 0, stream>>>(rgb, dte, w1T, b1, w2T, b2, w3T, b3,
                                    nrm, ipT, xpT, dtT, opT, Aneg,
                                    c1w, c1b, dtb, Dpw, outc, hfin);
}

// Round 11
// 626.827 us; speedup vs baseline: 1.0894x; 1.0894x over previous
//
#include <hip/hip_runtime.h>

typedef unsigned short u16;
typedef unsigned int u32;

__device__ __forceinline__ float2 up2(u32 u){
  union { u32 i; float f; } a, b;
  a.i = u << 16; b.i = u & 0xffff0000u;
  float2 r; r.x = a.f; r.y = b.f; return r;
}
__device__ __forceinline__ u16 f2bf(float f){
  union { float f; u32 i; } v; v.f = f;
  u32 x = v.i;
  return (u16)((x + 0x7fffu + ((x >> 16) & 1u)) >> 16);
}
__device__ __forceinline__ u32 pk2(float a, float b){
  return (u32)f2bf(a) | ((u32)f2bf(b) << 16);
}
__device__ __forceinline__ float silu_f(float x){ return x / (1.f + __expf(-x)); }
__device__ __forceinline__ float softplus_f(float x){
  return fmaxf(x, 0.f) + log1pf(__expf(-fabsf(x)));
}

// ---- transpose weights, A = -exp(A_log) --------------------------------
__global__ __launch_bounds__(256) void k_prep(
    const float* __restrict__ ipw, const float* __restrict__ xpw,
    const float* __restrict__ dtw, const float* __restrict__ opw,
    const float* __restrict__ w1, const float* __restrict__ w2,
    const float* __restrict__ w3, const float* __restrict__ alog,
    float* __restrict__ ipT, float* __restrict__ xpT,
    float* __restrict__ dtT, float* __restrict__ opT,
    float* __restrict__ w1T, float* __restrict__ w2T,
    float* __restrict__ w3T, float* __restrict__ Aneg)
{
  int t = blockIdx.x * 256 + threadIdx.x;
  if (t < 16384){ int o = t >> 6, c = t & 63; ipT[c * 256 + o] = ipw[t]; }
  if (t < 8192){ int o = t >> 7, d = t & 127; xpT[d * 64 + o] = xpw[t]; }
  if (t < 4096){ int d = t >> 5, r = t & 31; dtT[r * 128 + d] = dtw[t]; }
  if (t < 8192){ int o = t >> 7, d = t & 127; opT[d * 64 + o] = opw[t]; }
  if (t < 4096){ int o = t >> 6, c = t & 63;
                 w1T[c*64+o] = w1[t]; w2T[c*64+o] = w2[t]; w3T[c*64+o] = w3[t]; }
  if (t < 2048){ Aneg[t] = -__expf(alog[t]); }
}

// ---- fully fused: convin + 6 mamba blocks + conv3 ----------------------
// 256 blocks (1/CU). Block owns 32 positions, computes 48 (halo 8/side,
// need 6 for the 6 chained radius-1 convs). 8 waves x 6 positions/wave.
// Lane owns d_inner channels d0=lane, d1=64+lane.
// h state: bf16-packed, resident in VGPRs across all 6 steps (96 u32/thread).
// VGPR budget: the compiler's default heuristic targets 4-8 waves/EU
// (128/64 regs) regardless of our 152.5 KB LDS capping the CU at ONE
// block (= 2 waves/EU). amdgpu_waves_per_eu(1,2) — the MAX matters —
// legalizes a 256-VGPR allocation, fitting ~230 live regs with no spill.
// (R2: 512thr default -> 128 regs, 1.36 GB spill traffic; R8: 1024thr
// default -> 64 regs, 1.73 GB. Both passed, both spill-bound at ~560-613us.)
#define CPB 48
#define PPW 6

__global__ __attribute__((amdgpu_flat_work_group_size(512, 512), amdgpu_waves_per_eu(1, 2)))
void k_fused(
    const float* __restrict__ rgb, const float* __restrict__ dte,
    const float* __restrict__ w1T, const float* __restrict__ b1,
    const float* __restrict__ w2T, const float* __restrict__ b2,
    const float* __restrict__ w3T, const float* __restrict__ b3,
    const float* __restrict__ normw, const float* __restrict__ ipT,
    const float* __restrict__ xpT, const float* __restrict__ dtT,
    const float* __restrict__ opT, const float* __restrict__ Aneg,
    const float* __restrict__ c1w, const float* __restrict__ c1b,
    const float* __restrict__ dtb, const float* __restrict__ Dpw,
    float* __restrict__ outc, float* __restrict__ hfin)
{
  __shared__ __align__(16) float xcp[CPB][128];   // conv input (in_proj x half)
  __shared__ __align__(16) float xcs[CPB][128];   // conv out, reused as y*z
  __shared__ __align__(16) float dblS[CPB][64];   // x_proj out (dt|B|C); later out6
  __shared__ __align__(16) float xns[CPB][64];    // normalized x
  __shared__ __align__(16) float bA[CPB][64];     // rgbp base
  __shared__ __align__(16) float bB[CPB][64];     // dtep base
  __shared__ __align__(16) float ansS[16][129];   // A (s-major, padded)
  __shared__ __align__(16) float xpW[8192];       // x_proj weights
  __shared__ __align__(16) float dtW[4096];       // dt_proj weights

  const int tid = threadIdx.x;
  const int wv = tid >> 6, lane = tid & 63;
  const int b = blockIdx.x;
  const int batch = b >> 7;
  const int lbase = ((b & 127) << 5) - 8;         // local l of computed pos 0
  const int cpw = wv * PPW;
  const int d0 = lane, d1 = 64 + lane;

  // stage shared weights into LDS
  for (int i = tid; i < 8192; i += 512) xpW[i] = xpT[i];
  for (int i = tid; i < 4096; i += 512) dtW[i] = dtT[i];
  for (int i = tid; i < 2048; i += 512) ansS[i & 15][i >> 4] = Aneg[i];

  // per-lane constants
  const float cw00 = c1w[d0*3+0], cw01 = c1w[d0*3+1], cw02 = c1w[d0*3+2];
  const float cw10 = c1w[d1*3+0], cw11 = c1w[d1*3+1], cw12 = c1w[d1*3+2];
  const float cb0 = c1b[d0], cb1 = c1b[d1];
  const float tb0 = dtb[d0], tb1 = dtb[d1];
  const float dp0 = Dpw[d0], dp1 = Dpw[d1];
  const float nw = normw[lane];

  int lp[PPW];
  #pragma unroll
  for (int p = 0; p < PPW; p++) lp[p] = lbase + cpw + p;   // unclamped local l

  // ---- input 1x1 convs: bA = rgbp, bB = dtep (halo reads clamped) ------
  {
    const float* rp = rgb + (size_t)batch * 262144;
    const float* dq_ = dte + (size_t)batch * 262144;
    int lc[PPW];
    #pragma unroll
    for (int p = 0; p < PPW; p++) lc[p] = min(max(lp[p], 0), 4095);
    float accA[PPW], accB[PPW];
    float bb1 = b1[lane], bb2 = b2[lane];
    #pragma unroll
    for (int p = 0; p < PPW; p++){ accA[p] = bb1; accB[p] = bb2; }
    #pragma unroll 4
    for (int c = 0; c < 64; c++){
      float wA = w1T[c*64 + lane], wB = w2T[c*64 + lane];
      const float* rc = rp + c*4096;
      const float* dc = dq_ + c*4096;
      #pragma unroll
      for (int p = 0; p < PPW; p++){
        accA[p] = fmaf(wA, rc[lc[p]], accA[p]);
        accB[p] = fmaf(wB, dc[lc[p]], accB[p]);
      }
    }
    #pragma unroll
    for (int p = 0; p < PPW; p++){ bA[cpw+p][lane] = accA[p]; bB[cpw+p][lane] = accB[p]; }
  }

  // ---- pre: rmsnorm(rgbp) + in_proj -> xcp, zs (step 0 input) ----------
  float xnr[PPW], zs0[PPW], zs1[PPW];
  {
    #pragma unroll
    for (int p = 0; p < PPW; p++){
      float v = bA[cpw+p][lane];
      float ss = v * v;
      for (int m = 32; m > 0; m >>= 1) ss += __shfl_xor(ss, m);
      v = v * rsqrtf(ss * (1.f/64.f) + 1e-5f) * nw;
      xnr[p] = v; xns[cpw+p][lane] = v;
    }
    float a0[PPW]={}, a1[PPW]={}, a2[PPW]={}, a3[PPW]={};
    #pragma unroll 4
    for (int c = 0; c < 64; c++){
      float w0 = ipT[c*256 + lane];
      float w1 = ipT[c*256 + 64 + lane];
      float w2 = ipT[c*256 + 128 + lane];
      float w3 = ipT[c*256 + 192 + lane];
      #pragma unroll
      for (int p = 0; p < PPW; p++){
        float xv = xns[cpw+p][c];
        a0[p]=fmaf(w0,xv,a0[p]); a1[p]=fmaf(w1,xv,a1[p]);
        a2[p]=fmaf(w2,xv,a2[p]); a3[p]=fmaf(w3,xv,a3[p]);
      }
    }
    #pragma unroll
    for (int p = 0; p < PPW; p++){
      xcp[cpw+p][d0] = a0[p]; xcp[cpw+p][d1] = a1[p];
      zs0[p] = silu_f(a2[p]); zs1[p] = silu_f(a3[p]);
    }
  }

  // h state, bf16-packed (s even -> low, s odd -> high). Zero-init == hasH=0.
  u32 hp0[PPW][8] = {}, hp1[PPW][8] = {};

  #pragma unroll 1
  for (int k = 0; k < 6; k++){
    __syncthreads();                       // all waves' xcp (and LDS weights) ready

    // depthwise conv(3) + silu; guards: LDS bound (cp) and batch pad (l)
    float xc0[PPW], xc1[PPW];
    #pragma unroll
    for (int p = 0; p < PPW; p++){
      int cp = cpw + p;
      float am0=0.f, am1=0.f, ap0=0.f, ap1=0.f;
      if (cp > 0 && lp[p] > 0)       { am0 = xcp[cp-1][d0]; am1 = xcp[cp-1][d1]; }
      float a00 = xcp[cp][d0], a01 = xcp[cp][d1];
      if (cp < CPB-1 && lp[p] < 4095){ ap0 = xcp[cp+1][d0]; ap1 = xcp[cp+1][d1]; }
      float v0 = silu_f(fmaf(cw00,am0, fmaf(cw01,a00, fmaf(cw02,ap0, cb0))));
      float v1 = silu_f(fmaf(cw10,am1, fmaf(cw11,a01, fmaf(cw12,ap1, cb1))));
      xc0[p] = v0; xc1[p] = v1;
      xcs[cp][d0] = v0; xcs[cp][d1] = v1;
    }
    __syncthreads();                       // conv reads done; xcp may be overwritten

    // x_proj -> dblS[cp][o]  (o = lane)
    {
      float xa[PPW] = {};
      #pragma unroll 2
      for (int dq = 0; dq < 32; dq++){
        float w0 = xpW[(dq*4+0)*64 + lane], w1 = xpW[(dq*4+1)*64 + lane];
        float w2 = xpW[(dq*4+2)*64 + lane], w3 = xpW[(dq*4+3)*64 + lane];
        #pragma unroll
        for (int p = 0; p < PPW; p++){
          float4 xv = *(const float4*)&xcs[cpw+p][dq*4];
          xa[p] = fmaf(w0,xv.x, fmaf(w1,xv.y, fmaf(w2,xv.z, fmaf(w3,xv.w, xa[p]))));
        }
      }
      #pragma unroll
      for (int p = 0; p < PPW; p++) dblS[cpw+p][lane] = xa[p];
    }

    // dt_proj + softplus
    float dl0[PPW], dl1[PPW];
    {
      float da0[PPW], da1[PPW];
      #pragma unroll
      for (int p = 0; p < PPW; p++){ da0[p] = tb0; da1[p] = tb1; }
      #pragma unroll 4
      for (int r = 0; r < 32; r++){
        float w0 = dtW[r*128 + d0], w1 = dtW[r*128 + d1];
        #pragma unroll
        for (int p = 0; p < PPW; p++){
          float bv = dblS[cpw+p][r];
          da0[p] = fmaf(w0, bv, da0[p]); da1[p] = fmaf(w1, bv, da1[p]);
        }
      }
      #pragma unroll
      for (int p = 0; p < PPW; p++){ dl0[p] = softplus_f(da0[p]); dl1[p] = softplus_f(da1[p]); }
    }

    // h update + y (registers; bf16 repack except last step -> fp32 store)
    float y0[PPW] = {}, y1[PPW] = {};
    float bx0[PPW], bx1[PPW];
    #pragma unroll
    for (int p = 0; p < PPW; p++){ bx0[p] = dl0[p]*xc0[p]; bx1[p] = dl1[p]*xc1[p]; }
    if (k < 5){
      #pragma unroll
      for (int q = 0; q < 8; q++){
        float a0e = ansS[2*q][d0], a0o = ansS[2*q+1][d0];
        float a1e = ansS[2*q][d1], a1o = ansS[2*q+1][d1];
        #pragma unroll
        for (int p = 0; p < PPW; p++){
          int cp = cpw + p;
          float2 Bv = *(const float2*)&dblS[cp][32 + 2*q];
          float2 Cv = *(const float2*)&dblS[cp][48 + 2*q];
          float2 h0 = up2(hp0[p][q]);
          float2 h1 = up2(hp1[p][q]);
          float n0e = fmaf(__expf(dl0[p]*a0e), h0.x, bx0[p]*Bv.x);
          float n0o = fmaf(__expf(dl0[p]*a0o), h0.y, bx0[p]*Bv.y);
          float n1e = fmaf(__expf(dl1[p]*a1e), h1.x, bx1[p]*Bv.x);
          float n1o = fmaf(__expf(dl1[p]*a1o), h1.y, bx1[p]*Bv.y);
          y0[p] = fmaf(n0e, Cv.x, y0[p]); y0[p] = fmaf(n0o, Cv.y, y0[p]);
          y1[p] = fmaf(n1e, Cv.x, y1[p]); y1[p] = fmaf(n1o, Cv.y, y1[p]);
          hp0[p][q] = pk2(n0e, n0o);
          hp1[p][q] = pk2(n1e, n1o);
        }
      }
    } else {
      #pragma unroll
      for (int q = 0; q < 8; q++){
        float a0e = ansS[2*q][d0], a0o = ansS[2*q+1][d0];
        float a1e = ansS[2*q][d1], a1o = ansS[2*q+1][d1];
        #pragma unroll
        for (int p = 0; p < PPW; p++){
          int cp = cpw + p;
          float2 Bv = *(const float2*)&dblS[cp][32 + 2*q];
          float2 Cv = *(const float2*)&dblS[cp][48 + 2*q];
          float2 h0 = up2(hp0[p][q]);
          float2 h1 = up2(hp1[p][q]);
          float n0e = fmaf(__expf(dl0[p]*a0e), h0.x, bx0[p]*Bv.x);
          float n0o = fmaf(__expf(dl0[p]*a0o), h0.y, bx0[p]*Bv.y);
          float n1e = fmaf(__expf(dl1[p]*a1e), h1.x, bx1[p]*Bv.x);
          float n1o = fmaf(__expf(dl1[p]*a1o), h1.y, bx1[p]*Bv.y);
          y0[p] = fmaf(n0e, Cv.x, y0[p]); y0[p] = fmaf(n0o, Cv.y, y0[p]);
          y1[p] = fmaf(n1e, Cv.x, y1[p]); y1[p] = fmaf(n1o, Cv.y, y1[p]);
          if (cp >= 8 && cp < 40){
            size_t nI = (size_t)b*32 + (size_t)(cp - 8);
            float2 s0; s0.x = n0e; s0.y = n0o;
            float2 s1; s1.x = n1e; s1.y = n1o;
            *(float2*)(hfin + nI*2048 + (size_t)d0*16 + 2*q) = s0;
            *(float2*)(hfin + nI*2048 + (size_t)d1*16 + 2*q) = s1;
          }
        }
      }
    }

    // finish y, gate by silu(z) -> xcs (reused as yz buffer)
    #pragma unroll
    for (int p = 0; p < PPW; p++){
      int cp = cpw + p;
      float yy0 = fmaf(dp0, xc0[p], y0[p]);
      float yy1 = fmaf(dp1, xc1[p], y1[p]);
      xcs[cp][d0] = yy0 * zs0[p];
      xcs[cp][d1] = yy1 * zs1[p];
    }

    // out_proj
    float oa[PPW] = {};
    #pragma unroll 2
    for (int dq = 0; dq < 32; dq++){
      float w0 = opT[(dq*4+0)*64 + lane], w1 = opT[(dq*4+1)*64 + lane];
      float w2 = opT[(dq*4+2)*64 + lane], w3 = opT[(dq*4+3)*64 + lane];
      #pragma unroll
      for (int p = 0; p < PPW; p++){
        float4 yv = *(const float4*)&xcs[cpw+p][dq*4];
        oa[p] = fmaf(w0,yv.x, fmaf(w1,yv.y, fmaf(w2,yv.z, fmaf(w3,yv.w, oa[p]))));
      }
    }

    if (k < 5){
      // residual + base + rmsnorm + in_proj for next step
      const float (*bs_)[64] = (k & 1) ? bA : bB;
      #pragma unroll
      for (int p = 0; p < PPW; p++){
        int cp = cpw + p;
        float v = oa[p] + xnr[p] + bs_[cp][lane];
        float ss = v * v;
        for (int m = 32; m > 0; m >>= 1) ss += __shfl_xor(ss, m);
        v = v * rsqrtf(ss * (1.f/64.f) + 1e-5f) * nw;
        xnr[p] = v; xns[cp][lane] = v;
      }
      float a0[PPW]={}, a1[PPW]={}, a2[PPW]={}, a3[PPW]={};
      #pragma unroll 4
      for (int c = 0; c < 64; c++){
        float w0 = ipT[c*256 + lane];
        float w1 = ipT[c*256 + 64 + lane];
        float w2 = ipT[c*256 + 128 + lane];
        float w3 = ipT[c*256 + 192 + lane];
        #pragma unroll
        for (int p = 0; p < PPW; p++){
          float xv = xns[cpw+p][c];
          a0[p]=fmaf(w0,xv,a0[p]); a1[p]=fmaf(w1,xv,a1[p]);
          a2[p]=fmaf(w2,xv,a2[p]); a3[p]=fmaf(w3,xv,a3[p]);
        }
      }
      #pragma unroll
      for (int p = 0; p < PPW; p++){
        int cp = cpw + p;
        xcp[cp][d0] = a0[p]; xcp[cp][d1] = a1[p];
        zs0[p] = silu_f(a2[p]); zs1[p] = silu_f(a3[p]);
      }
    } else {
      #pragma unroll
      for (int p = 0; p < PPW; p++) dblS[cpw+p][lane] = oa[p] + xnr[p];  // out6
    }
  }

  // ---- final 1x1 conv (wave-local rows of dblS) ------------------------
  {
    float o3[PPW];
    float bb3 = b3[lane];
    #pragma unroll
    for (int p = 0; p < PPW; p++) o3[p] = bb3;
    #pragma unroll 2
    for (int cq = 0; cq < 16; cq++){
      float w0 = w3T[(cq*4+0)*64 + lane], w1 = w3T[(cq*4+1)*64 + lane];
      float w2 = w3T[(cq*4+2)*64 + lane], w3v = w3T[(cq*4+3)*64 + lane];
      #pragma unroll
      for (int p = 0; p < PPW; p++){
        float4 vv = *(const float4*)&dblS[cpw+p][cq*4];
        o3[p] = fmaf(w0,vv.x, fmaf(w1,vv.y, fmaf(w2,vv.z, fmaf(w3v,vv.w, o3[p]))));
      }
    }
    #pragma unroll
    for (int p = 0; p < PPW; p++){
      int cp = cpw + p;
      if (cp >= 8 && cp < 40)
        outc[(size_t)batch*262144 + (size_t)lane*4096 + lp[p]] = o3[p];
    }
  }
}

extern "C" void kernel_launch(void* const* d_in, const int* in_sizes, int n_in,
                              void* d_out, int out_size, void* d_ws, size_t ws_size,
                              hipStream_t stream)
{
  const float* rgb  = (const float*)d_in[0];
  const float* dte  = (const float*)d_in[1];
  const float* w1   = (const float*)d_in[2];
  const float* b1   = (const float*)d_in[3];
  const float* w2   = (const float*)d_in[4];
  const float* b2   = (const float*)d_in[5];
  const float* w3   = (const float*)d_in[6];
  const float* b3   = (const float*)d_in[7];
  const float* nrm  = (const float*)d_in[8];
  const float* ipw  = (const float*)d_in[9];
  const float* c1w  = (const float*)d_in[10];
  const float* c1b  = (const float*)d_in[11];
  const float* xpw  = (const float*)d_in[12];
  const float* dtw  = (const float*)d_in[13];
  const float* dtb  = (const float*)d_in[14];
  const float* alog = (const float*)d_in[15];
  const float* Dpw  = (const float*)d_in[16];
  const float* opw  = (const float*)d_in[17];

  float* outc = (float*)d_out;
  float* hfin = outc + 524288;          // final fp32 h lives in d_out

  float* wb   = (float*)d_ws;
  float* ipT  = wb;                     // [64][256]
  float* xpT  = wb + 16384;             // [128][64]
  float* dtT  = wb + 24576;             // [32][128]
  float* opT  = wb + 28672;             // [128][64]
  float* w1T  = wb + 36864;             // [64][64]
  float* w2T  = wb + 40960;
  float* w3T  = wb + 45056;
  float* Aneg = wb + 49152;             // [128][16]

  k_prep<<<64, 256, 0, stream>>>(ipw, xpw, dtw, opw, w1, w2, w3, alog,
                                 ipT, xpT, dtT, opT, w1T, w2T, w3T, Aneg);
  k_fused<<<256, 512, 0, stream>>>(rgb, dte, w1T, b1, w2T, b2, w3T, b3,
                                   nrm, ipT, xpT, dtT, opT, Aneg,
                                   c1w, c1b, dtb, Dpw, outc, hfin);
}